// Round 2
// baseline (11537.408 us; speedup 1.0000x reference)
//
#include <hip/hip_runtime.h>
#include <hip/hip_bf16.h>

// RSSM scan, restructured:
//  - reset+za tiny kernel; fused [za|h] @ [Wi;Wh] GEMM for r/z gates (gi+gh linear);
//    separate gi_n / gh_n GEMMs (rg multiplies hn only) -> one 256-block dispatch
//  - embed @ post_W1[D:,:] precomputed for all t (off critical path)
//  - priors deferred to one batched pass after the scan
//  - all GEMMs bf16 MFMA 16x16x32, m97 structure (128x128 tile, BK=64, global_load_lds w16)
// R1 fix: reset is marshalled as int32 (bool -> const int*), was read as bytes.

using namespace std;

typedef __attribute__((ext_vector_type(4))) float  f32x4;
typedef __attribute__((ext_vector_type(8))) short  short8;
typedef __attribute__((ext_vector_type(4))) short  short4v;

#define T_STEPS 64
#define BATCH   512

__device__ __forceinline__ float b2f(short s) {
    union { unsigned u; float f; } v; v.u = ((unsigned)(unsigned short)s) << 16; return v.f;
}
__device__ __forceinline__ short f2b(float f) {  // RNE
    unsigned u = __float_as_uint(f);
    unsigned r = u + 0x7FFF + ((u >> 16) & 1);
    return (short)(r >> 16);
}
__device__ __forceinline__ void async_copy16(const void* g, void* l) {
    __builtin_amdgcn_global_load_lds(
        (__attribute__((address_space(1))) void*)(void*)(size_t)(const char*)g,
        (__attribute__((address_space(3))) void*)l, 16, 0, 0);
}
__device__ __forceinline__ float sigmoidf_(float x) { return 1.f / (1.f + __expf(-x)); }
__device__ __forceinline__ float eluf_(float x) { return x > 0.f ? x : expm1f(x); }
__device__ __forceinline__ float softplusf_(float x) {
    return fmaxf(x, 0.f) + log1pf(__expf(-fabsf(x)));
}

// ---------------------------------------------------------------------------
// GEMM core: C_tile(128x128) at (row0,col0) = A(MxK) * B^T, B stored N-major (NxK) bf16.
// 256 threads, 4 waves in 2x2, wave tile 64x64, BK=64. A is bf16 (async path) or f32
// (load+cvt+ds_write path).
// ---------------------------------------------------------------------------
template <bool AF32>
__device__ __forceinline__ void gemm_core(const void* Aptr, const short* B, int K,
                                          int lda, int ldb, int row0, int col0,
                                          short* lA, short* lB, f32x4 acc[4][4]) {
    const int tid = threadIdx.x, lane = tid & 63, wave = tid >> 6;
    const int wm = wave & 1, wn = wave >> 1;
#pragma unroll
    for (int mt = 0; mt < 4; ++mt)
#pragma unroll
        for (int nt = 0; nt < 4; ++nt) acc[mt][nt] = f32x4{0.f, 0.f, 0.f, 0.f};

    const short* Ab = (const short*)Aptr;
    const float* Af = (const float*)Aptr;
    const int arow = wm * 64 + (lane & 15);
    const int brow = wn * 64 + (lane & 15);
    const int kq   = (lane >> 4) << 3;

    for (int k0 = 0; k0 < K; k0 += 64) {
        __syncthreads();
        if (AF32) {
#pragma unroll
            for (int i = 0; i < 8; ++i) {
                int idx = i * 256 + tid;
                int r = idx >> 4, c = (idx & 15) << 2;
                const float4 v = *(const float4*)(Af + (size_t)(row0 + r) * lda + k0 + c);
                short4v s; s.x = f2b(v.x); s.y = f2b(v.y); s.z = f2b(v.z); s.w = f2b(v.w);
                *(short4v*)&lA[r * 64 + c] = s;
            }
        } else {
#pragma unroll
            for (int i = 0; i < 4; ++i) {
                int r = i * 32 + wave * 8 + (lane >> 3);
                int c = (lane & 7) << 3;
                async_copy16(Ab + (size_t)(row0 + r) * lda + k0 + c, &lA[(i * 32 + wave * 8) * 64]);
            }
        }
#pragma unroll
        for (int i = 0; i < 4; ++i) {
            int r = i * 32 + wave * 8 + (lane >> 3);
            int c = (lane & 7) << 3;
            async_copy16(B + (size_t)(col0 + r) * ldb + k0 + c, &lB[(i * 32 + wave * 8) * 64]);
        }
        __syncthreads();
#pragma unroll
        for (int kk = 0; kk < 64; kk += 32) {
            short8 af[4], bf_[4];
#pragma unroll
            for (int mt = 0; mt < 4; ++mt) af[mt] = *(short8*)&lA[(arow + mt * 16) * 64 + kk + kq];
#pragma unroll
            for (int nt = 0; nt < 4; ++nt) bf_[nt] = *(short8*)&lB[(brow + nt * 16) * 64 + kk + kq];
#pragma unroll
            for (int mt = 0; mt < 4; ++mt)
#pragma unroll
                for (int nt = 0; nt < 4; ++nt)
                    acc[mt][nt] = __builtin_amdgcn_mfma_f32_16x16x32_bf16(af[mt], bf_[nt], acc[mt][nt], 0, 0, 0);
        }
    }
}

struct Epi {
    const float* bias;   // nullable, [col]
    const short* add;    // nullable bf16 addend matrix
    int add_ld;
    float* Cf; int ldcf; // nullable f32 out
    short* Cb; int ldcb; // nullable bf16 out
    int elu;
};

template <bool AF32>
__global__ __launch_bounds__(256, 2) void gemm_k(const void* A, const short* B, int K,
                                                 int lda, int ldb, int mtiles, Epi ep) {
    __shared__ short lA[128 * 64];
    __shared__ short lB[128 * 64];
    const int bm = blockIdx.x % mtiles, bn = blockIdx.x / mtiles;
    f32x4 acc[4][4];
    gemm_core<AF32>(A, B, K, lda, ldb, bm * 128, bn * 128, lA, lB, acc);
    const int lane = threadIdx.x & 63, wave = threadIdx.x >> 6;
    const int wm = wave & 1, wn = wave >> 1;
    const int rbase = bm * 128 + wm * 64 + ((lane >> 4) << 2);
    const int cbase = bn * 128 + wn * 64 + (lane & 15);
#pragma unroll
    for (int mt = 0; mt < 4; ++mt)
#pragma unroll
        for (int nt = 0; nt < 4; ++nt)
#pragma unroll
            for (int r = 0; r < 4; ++r) {
                const int row = rbase + mt * 16 + r;
                const int col = cbase + nt * 16;
                float x = acc[mt][nt][r];
                if (ep.bias) x += ep.bias[col];
                if (ep.add)  x += b2f(ep.add[(size_t)row * ep.add_ld + col]);
                if (ep.elu)  x = eluf_(x);
                if (ep.Cf) ep.Cf[(size_t)row * ep.ldcf + col] = x;
                if (ep.Cb) ep.Cb[(size_t)row * ep.ldcb + col] = f2b(x);
            }
}

// Three gate GEMMs in one dispatch: blocks 0..127 RZ, 128..191 IN, 192..255 HN.
__global__ __launch_bounds__(256, 2) void gates_k(const short* Xrz, const short* Wrz,
                                                  const short* Win, const short* Whn,
                                                  float* Grz, float* Gin, float* Ghn) {
    __shared__ short lA[128 * 64];
    __shared__ short lB[128 * 64];
    int bid = blockIdx.x;
    const short *A, *B; float* C; int K, lda, ldb, ldc;
    if (bid < 128)      { A = Xrz;        B = Wrz; C = Grz; K = 3072; lda = 3072; ldb = 3072; ldc = 4096; }
    else if (bid < 192) { bid -= 128; A = Xrz;        B = Win; C = Gin; K = 1024; lda = 3072; ldb = 1024; ldc = 2048; }
    else                { bid -= 192; A = Xrz + 1024; B = Whn; C = Ghn; K = 2048; lda = 3072; ldb = 2048; ldc = 2048; }
    const int bm = bid & 3, bn = bid >> 2;
    f32x4 acc[4][4];
    gemm_core<false>(A, B, K, lda, ldb, bm * 128, bn * 128, lA, lB, acc);
    const int lane = threadIdx.x & 63, wave = threadIdx.x >> 6;
    const int wm = wave & 1, wn = wave >> 1;
    const int rbase = bm * 128 + wm * 64 + ((lane >> 4) << 2);
    const int cbase = bn * 128 + wn * 64 + (lane & 15);
#pragma unroll
    for (int mt = 0; mt < 4; ++mt)
#pragma unroll
        for (int nt = 0; nt < 4; ++nt)
#pragma unroll
            for (int r = 0; r < 4; ++r)
                C[(size_t)(rbase + mt * 16 + r) * ldc + cbase + nt * 16] = acc[mt][nt][r];
}

// ---------------------------------------------------------------------------
// Weight transpose/pack: dst(N-major bf16)[n*dld + k] = src(f32)[k*sld + n]
// ---------------------------------------------------------------------------
struct TJobs {
    const float* src[9]; short* dst[9];
    int K[9], N[9], sld[9], dld[9], pre[10];
};
__global__ void transpose_pack(TJobs tj) {
    __shared__ float tile[64][65];
    int bid = blockIdx.x;
    int j = 0;
    while (bid >= tj.pre[j + 1]) ++j;
    const int rel = bid - tj.pre[j];
    const int ktiles = tj.K[j] >> 6;
    const int tk = rel % ktiles, tn = rel / ktiles;
    const float* src = tj.src[j];
    const int sld = tj.sld[j];
    const int tid = threadIdx.x;
#pragma unroll
    for (int i = 0; i < 16; ++i) {
        int idx = i * 256 + tid;
        int r = idx >> 6, c = idx & 63;
        tile[r][c] = src[(size_t)(tk * 64 + r) * sld + tn * 64 + c];
    }
    __syncthreads();
    short* dst = tj.dst[j];
    const int dld = tj.dld[j];
#pragma unroll
    for (int i = 0; i < 16; ++i) {
        int idx = i * 256 + tid;
        int r = idx >> 6, c = idx & 63;
        dst[(size_t)(tn * 64 + r) * dld + tk * 64 + c] = f2b(tile[c][r]);
    }
}

__global__ void init_state_k(const float* in_state, float* h_state, float* z_state) {
    int idx = blockIdx.x * 256 + threadIdx.x;   // 512*2080
    int b = idx / 2080, c = idx % 2080;
    float v = in_state[idx];
    if (c < 2048) h_state[b * 2048 + c] = v;
    else          z_state[b * 32 + (c - 2048)] = v;
}

// reset + za = elu([z|a] @ za_W + za_b) (bf16 out), and reset-applied h (bf16 + f32)
__global__ void za_hreset_k(const float* action_t, const int* reset_t,
                            const float* za_W, const float* za_b,
                            const float* z_state, float* h_state, short* X_rz) {
    int idx = blockIdx.x * 256 + threadIdx.x;
    if (idx < 512 * 1024) {
        int b = idx >> 10, n = idx & 1023;
        bool r = reset_t[b] != 0;
        float sum = za_b[n];
        if (!r) {
#pragma unroll 8
            for (int k = 0; k < 32; ++k) sum += z_state[b * 32 + k] * za_W[k * 1024 + n];
        }
        const float* a = action_t + b * 7;
#pragma unroll
        for (int k = 0; k < 7; ++k) sum += a[k] * za_W[(32 + k) * 1024 + n];
        X_rz[b * 3072 + n] = f2b(eluf_(sum));
    } else {
        int i2 = idx - 512 * 1024;
        int b = i2 >> 11, c = i2 & 2047;
        bool r = reset_t[b] != 0;
        float h = r ? 0.f : h_state[b * 2048 + c];
        h_state[b * 2048 + c] = h;
        X_rz[b * 3072 + 1024 + c] = f2b(h);
    }
}

// GRU gates -> h_new (f32 state + bf16 operand + states output)
__global__ void gate_k(const float* Grz, const float* Gin, const float* Ghn,
                       const float* bi, const float* bh, float* h_state,
                       short* Xpost, float* states_t) {
    int idx = blockIdx.x * 256 + threadIdx.x;   // 512*2048
    int b = idx >> 11, j = idx & 2047;
    float rg = sigmoidf_(Grz[(size_t)b * 4096 + j] + bi[j] + bh[j]);
    float zg = sigmoidf_(Grz[(size_t)b * 4096 + 2048 + j] + bi[2048 + j] + bh[2048 + j]);
    float nv = tanhf(Gin[idx] + bi[4096 + j] + rg * (Ghn[idx] + bh[4096 + j]));
    float h = h_state[idx];
    float hn = (1.f - zg) * nv + zg * h;
    h_state[idx] = hn;
    Xpost[idx] = f2b(hn);
    states_t[(size_t)b * 2080 + j] = hn;
}

// Head: (rows x 1024) bf16 @ W2^T(64x1024) + b2 -> mean/std(+0.1 softplus), optional sample
__global__ void head_k(const short* U, const short* W2, const float* b2, float* out,
                       const float* noise_t, float* z_state, float* states_t, int write_sample) {
    __shared__ short urow[1024];
    __shared__ float part[256];
    __shared__ float tot[64];
    const int b = blockIdx.x, tid = threadIdx.x;
    *(short4v*)&urow[tid * 4] = *(const short4v*)&U[(size_t)b * 1024 + tid * 4];
    __syncthreads();
    const int n = tid & 63, s = tid >> 6;
    const short* w  = W2 + n * 1024 + s * 256;
    const short* ur = urow + s * 256;
    float sum = 0.f;
#pragma unroll 4
    for (int k = 0; k < 256; k += 8) {
        short8 wv = *(const short8*)(w + k);
        short8 uv = *(const short8*)(ur + k);
#pragma unroll
        for (int j = 0; j < 8; ++j) sum = fmaf(b2f(uv[j]), b2f(wv[j]), sum);
    }
    part[tid] = sum;
    __syncthreads();
    if (tid < 64) tot[tid] = part[tid] + part[tid + 64] + part[tid + 128] + part[tid + 192] + b2[tid];
    __syncthreads();
    if (tid < 32) {
        float mean = tot[tid];
        float stdv = softplusf_(tot[tid + 32]) + 0.1f;
        out[(size_t)b * 64 + tid] = mean;
        out[(size_t)b * 64 + 32 + tid] = stdv;
        if (write_sample) {
            float smp = mean + stdv * noise_t[b * 32 + tid];
            z_state[b * 32 + tid] = smp;
            states_t[(size_t)b * 2080 + 2048 + tid] = smp;
        }
    }
}

// ---------------------------------------------------------------------------
// ws layout (bytes)
// ---------------------------------------------------------------------------
constexpr size_t OFF_WRZ   = 0;                          // 4096x3072 bf16
constexpr size_t OFF_WIN   = OFF_WRZ + 25165824;         // 2048x1024 bf16
constexpr size_t OFF_WHN   = OFF_WIN + 4194304;          // 2048x2048 bf16
constexpr size_t OFF_W1H   = OFF_WHN + 8388608;          // 1024x2048 bf16
constexpr size_t OFF_W1E   = OFF_W1H + 4194304;          // 1024x1536 bf16
constexpr size_t OFF_PW1   = OFF_W1E + 3145728;          // 1024x2048 bf16
constexpr size_t OFF_W2P   = OFF_PW1 + 4194304;          // 64x1024 bf16
constexpr size_t OFF_W2R   = OFF_W2P + 131072;           // 64x1024 bf16
constexpr size_t OFF_EPART = OFF_W2R + 131072;           // 32768x1024 bf16
constexpr size_t OFF_XRZ   = OFF_EPART + 67108864;       // 512x3072 bf16
constexpr size_t OFF_XPOST = OFF_XRZ + 3145728;          // 512x2048 bf16
constexpr size_t OFF_U     = OFF_XPOST + 2097152;        // 512x1024 bf16
constexpr size_t OFF_GRZ   = OFF_U + 1048576;            // 512x4096 f32
constexpr size_t OFF_GIN   = OFF_GRZ + 8388608;          // 512x2048 f32
constexpr size_t OFF_GHN   = OFF_GIN + 4194304;          // 512x2048 f32
constexpr size_t OFF_H     = OFF_GHN + 4194304;          // 512x2048 f32
constexpr size_t OFF_Z     = OFF_H + 4194304;            // 512x32 f32
constexpr size_t OFF_UPRI  = OFF_Z + 65536;              // 8192x1024 bf16
// total ~153 MB

extern "C" void kernel_launch(void* const* d_in, const int* in_sizes, int n_in,
                              void* d_out, int out_size, void* d_ws, size_t ws_size,
                              hipStream_t stream) {
    const float* embed    = (const float*)d_in[0];
    const float* action   = (const float*)d_in[1];
    const float* noise    = (const float*)d_in[2];
    const float* in_state = (const float*)d_in[3];
    const float* za_W     = (const float*)d_in[4];
    const float* za_b     = (const float*)d_in[5];
    const float* gru_Wi   = (const float*)d_in[6];
    const float* gru_Wh   = (const float*)d_in[7];
    const float* gru_bi   = (const float*)d_in[8];
    const float* gru_bh   = (const float*)d_in[9];
    const float* prior_W1 = (const float*)d_in[10];
    const float* prior_b1 = (const float*)d_in[11];
    const float* prior_W2 = (const float*)d_in[12];
    const float* prior_b2 = (const float*)d_in[13];
    const float* post_W1  = (const float*)d_in[14];
    const float* post_b1  = (const float*)d_in[15];
    const float* post_W2  = (const float*)d_in[16];
    const float* post_b2  = (const float*)d_in[17];
    const int*   reset    = (const int*)d_in[18];   // bool marshalled as int32

    char* ws = (char*)d_ws;
    short* W_rz  = (short*)(ws + OFF_WRZ);
    short* Wi_n  = (short*)(ws + OFF_WIN);
    short* Wh_n  = (short*)(ws + OFF_WHN);
    short* W1h   = (short*)(ws + OFF_W1H);
    short* W1e   = (short*)(ws + OFF_W1E);
    short* PW1   = (short*)(ws + OFF_PW1);
    short* W2p   = (short*)(ws + OFF_W2P);
    short* W2r   = (short*)(ws + OFF_W2R);
    short* epart = (short*)(ws + OFF_EPART);
    short* X_rz  = (short*)(ws + OFF_XRZ);
    short* Xpost = (short*)(ws + OFF_XPOST);
    short* Ubuf  = (short*)(ws + OFF_U);
    float* Grz   = (float*)(ws + OFF_GRZ);
    float* Gin   = (float*)(ws + OFF_GIN);
    float* Ghn   = (float*)(ws + OFF_GHN);
    float* h_st  = (float*)(ws + OFF_H);
    float* z_st  = (float*)(ws + OFF_Z);
    short* Upri  = (short*)(ws + OFF_UPRI);

    float* priors = (float*)d_out;
    float* posts  = priors + (size_t)T_STEPS * BATCH * 64;
    float* states = posts + (size_t)T_STEPS * BATCH * 64;

    dim3 blk(256);

    // 1. transpose/pack weights to bf16 N-major
    TJobs tj;
    const float* srcs[9] = { gru_Wi, gru_Wh, gru_Wi + 4096, gru_Wh + 4096,
                             post_W1, post_W1 + (size_t)2048 * 1024, prior_W1,
                             post_W2, prior_W2 };
    short* dsts[9] = { W_rz, W_rz + 1024, Wi_n, Wh_n, W1h, W1e, PW1, W2p, W2r };
    int Ks[9]   = { 1024, 2048, 1024, 2048, 2048, 1536, 2048, 1024, 1024 };
    int Ns[9]   = { 4096, 4096, 2048, 2048, 1024, 1024, 1024, 64, 64 };
    int slds[9] = { 6144, 6144, 6144, 6144, 1024, 1024, 1024, 64, 64 };
    int dlds[9] = { 3072, 3072, 1024, 2048, 2048, 1536, 2048, 1024, 1024 };
    tj.pre[0] = 0;
    for (int j = 0; j < 9; ++j) {
        tj.src[j] = srcs[j]; tj.dst[j] = dsts[j];
        tj.K[j] = Ks[j]; tj.N[j] = Ns[j]; tj.sld[j] = slds[j]; tj.dld[j] = dlds[j];
        tj.pre[j + 1] = tj.pre[j] + (Ks[j] >> 6) * (Ns[j] >> 6);
    }
    transpose_pack<<<tj.pre[9], blk, 0, stream>>>(tj);

    // 2. init recurrent state
    init_state_k<<<(512 * 2080) / 256, blk, 0, stream>>>(in_state, h_st, z_st);

    // 3. precompute e_part = embed @ post_W1[D:,:]  (bf16 out)
    {
        Epi ep{}; ep.Cb = epart; ep.ldcb = 1024;
        gemm_k<true><<<256 * 8, blk, 0, stream>>>(embed, W1e, 1536, 1536, 1536, 256, ep);
    }

    // 4. sequential scan
    for (int t = 0; t < T_STEPS; ++t) {
        za_hreset_k<<<6144, blk, 0, stream>>>(action + (size_t)t * 512 * 7, reset + (size_t)t * 512,
                                              za_W, za_b, z_st, h_st, X_rz);
        gates_k<<<256, blk, 0, stream>>>(X_rz, W_rz, Wi_n, Wh_n, Grz, Gin, Ghn);
        gate_k<<<4096, blk, 0, stream>>>(Grz, Gin, Ghn, gru_bi, gru_bh, h_st, Xpost,
                                         states + (size_t)t * 512 * 2080);
        Epi ep1{}; ep1.bias = post_b1; ep1.add = epart + (size_t)t * 512 * 1024;
        ep1.add_ld = 1024; ep1.Cb = Ubuf; ep1.ldcb = 1024; ep1.elu = 1;
        gemm_k<false><<<4 * 8, blk, 0, stream>>>(Xpost, W1h, 2048, 2048, 2048, 4, ep1);
        head_k<<<512, blk, 0, stream>>>(Ubuf, W2p, post_b2, posts + (size_t)t * 512 * 64,
                                        noise + (size_t)t * 512 * 32, z_st,
                                        states + (size_t)t * 512 * 2080, 1);
    }

    // 5. deferred priors, 4 chunks of 16 timesteps
    for (int c = 0; c < 4; ++c) {
        Epi ep2{}; ep2.bias = prior_b1; ep2.elu = 1; ep2.Cb = Upri; ep2.ldcb = 1024;
        gemm_k<true><<<64 * 8, blk, 0, stream>>>(states + (size_t)c * 16 * 512 * 2080, PW1,
                                                 2048, 2080, 2048, 64, ep2);
        head_k<<<8192, blk, 0, stream>>>(Upri, W2r, prior_b2, priors + (size_t)c * 8192 * 64,
                                         nullptr, nullptr, nullptr, 0);
    }
    (void)ws_size; (void)out_size; (void)n_in; (void)in_sizes;
}